// Round 1
// baseline (667.735 us; speedup 1.0000x reference)
//
#include <hip/hip_runtime.h>
#include <math.h>

#define NB1 1024          // blocks in pass 1
#define TPB 256           // threads per block
#define WAVES_PER_BLOCK (TPB / 64)
#define GROUPS_PER_WAVE 16                      // 4 lanes per row-group
#define TOTAL_GROUPS (NB1 * WAVES_PER_BLOCK * GROUPS_PER_WAVE)   // 65536
#define NLEAD (TPB / 4)                         // leaders per block = 64
#define NBCAND (NLEAD * 5)                      // 320 block-local candidates
#define NCAND (NB1 * 5)                         // 5120 global candidates

constexpr float EPS = 1e-6f;

__device__ __forceinline__ bool better(float v, int i, float bv, int bi) {
    // strictly-greater wins; on exact tie, lower row index wins (jax top_k order)
    return (v > bv) || (v == bv && i < bi);
}

__device__ __forceinline__ void insert5(float nv, int ni, float tv[5], int ti[5]) {
    // rows arrive in increasing index order per group, so a value equal to
    // tv[4] has a larger index and correctly loses -> simple reject is exact
    if (nv > tv[4]) {
        #pragma unroll
        for (int j = 0; j < 5; j++) {           // bubble-insert, keeps sorted desc
            bool b = better(nv, ni, tv[j], ti[j]);
            float ov = tv[j]; int oi = ti[j];
            if (b) { tv[j] = nv; ti[j] = ni; nv = ov; ni = oi; }
        }
    }
}

__global__ __launch_bounds__(TPB) void sim_block_topk(
    const float* __restrict__ W, const int* __restrict__ qidx,
    int V, float* __restrict__ bv, int* __restrict__ bi)
{
    const int tid  = threadIdx.x;
    const int lane = tid & 63;
    const int sub  = lane & 3;                  // chunk id within 4-lane group
    const int grp  = lane >> 2;                 // group within wave, 0..15
    const int wave = tid >> 6;
    const int groupGlobal =
        (blockIdx.x * WAVES_PER_BLOCK + wave) * GROUPS_PER_WAVE + grp;

    const int q = qidx[0];

    // q fragment: lane covers elements {sub*4 + j*16 .. +3} for j=0..7 (32 floats)
    float4 qv[8];
    const float4* Q4 = (const float4*)(W + (size_t)q * 128);
    #pragma unroll
    for (int j = 0; j < 8; j++) qv[j] = Q4[sub + 4 * j];

    float qn2 = 0.f;
    #pragma unroll
    for (int j = 0; j < 8; j++)
        qn2 += qv[j].x*qv[j].x + qv[j].y*qv[j].y + qv[j].z*qv[j].z + qv[j].w*qv[j].w;
    qn2 += __shfl_xor(qn2, 1);
    qn2 += __shfl_xor(qn2, 2);
    const float qn = sqrtf(qn2);

    // per-lane register top-5 (redundant across the 4 lanes of a group ->
    // uniform control flow in the hot loop; leader writes at the end)
    float tv[5]; int ti[5];
    #pragma unroll
    for (int j = 0; j < 5; j++) { tv[j] = -INFINITY; ti[j] = 0x7fffffff; }

    // each group owns PAIRS of consecutive rows: 16 dwordx4 in flight per
    // iteration (2x MLP vs single-row), group footprint 1 KB contiguous.
    // V is even and base is even, so base < V implies base+1 < V.
    for (int base = groupGlobal * 2; base < V; base += 2 * TOTAL_GROUPS) {
        const float4* Wr = (const float4*)(W + (size_t)base * 128);
        float4 a[8], b[8];
        #pragma unroll
        for (int j = 0; j < 8; j++) a[j] = Wr[sub + 4 * j];          // row base
        #pragma unroll
        for (int j = 0; j < 8; j++) b[j] = Wr[32 + sub + 4 * j];     // row base+1

        // per-row arithmetic identical (bitwise) to previous kernel version
        float dot0 = 0.f, nr0 = 0.f, dot1 = 0.f, nr1 = 0.f;
        #pragma unroll
        for (int j = 0; j < 8; j++) {
            dot0 += a[j].x*qv[j].x + a[j].y*qv[j].y + a[j].z*qv[j].z + a[j].w*qv[j].w;
            nr0  += a[j].x*a[j].x  + a[j].y*a[j].y  + a[j].z*a[j].z  + a[j].w*a[j].w;
        }
        #pragma unroll
        for (int j = 0; j < 8; j++) {
            dot1 += b[j].x*qv[j].x + b[j].y*qv[j].y + b[j].z*qv[j].z + b[j].w*qv[j].w;
            nr1  += b[j].x*b[j].x  + b[j].y*b[j].y  + b[j].z*b[j].z  + b[j].w*b[j].w;
        }
        // 2 shfl stages per quantity (4-lane group) -> all 4 lanes hold sums
        dot0 += __shfl_xor(dot0, 1); dot0 += __shfl_xor(dot0, 2);
        nr0  += __shfl_xor(nr0,  1); nr0  += __shfl_xor(nr0,  2);
        dot1 += __shfl_xor(dot1, 1); dot1 += __shfl_xor(dot1, 2);
        nr1  += __shfl_xor(nr1,  1); nr1  += __shfl_xor(nr1,  2);

        float sim0 = dot0 / fmaxf(qn * sqrtf(nr0), EPS);
        float sim1 = dot1 / fmaxf(qn * sqrtf(nr1), EPS);
        insert5(sim0, base,     tv, ti);
        insert5(sim1, base + 1, tv, ti);
    }

    // ---- block combine: 64 leaders x 5 -> block top-5 (parallel argmax) ----
    __shared__ float s_v[NBCAND];
    __shared__ int   s_i[NBCAND];
    __shared__ float sw_v[WAVES_PER_BLOCK];
    __shared__ int   sw_i[WAVES_PER_BLOCK], sw_p[WAVES_PER_BLOCK];

    if (sub == 0) {
        const int leader = tid >> 2;
        #pragma unroll
        for (int j = 0; j < 5; j++) { s_v[leader*5 + j] = tv[j]; s_i[leader*5 + j] = ti[j]; }
    }
    __syncthreads();

    for (int k = 0; k < 5; k++) {
        float v = -INFINITY; int i = 0x7fffffff; int p = 0;
        for (int e = tid; e < NBCAND; e += TPB) {
            if (better(s_v[e], s_i[e], v, i)) { v = s_v[e]; i = s_i[e]; p = e; }
        }
        #pragma unroll
        for (int m = 32; m >= 1; m >>= 1) {
            float ov = __shfl_xor(v, m);
            int   oi = __shfl_xor(i, m);
            int   op = __shfl_xor(p, m);
            if (better(ov, oi, v, i)) { v = ov; i = oi; p = op; }
        }
        if (lane == 0) { sw_v[wave] = v; sw_i[wave] = i; sw_p[wave] = p; }
        __syncthreads();
        if (tid == 0) {
            for (int w = 1; w < WAVES_PER_BLOCK; w++)
                if (better(sw_v[w], sw_i[w], sw_v[0], sw_i[0])) {
                    sw_v[0] = sw_v[w]; sw_i[0] = sw_i[w]; sw_p[0] = sw_p[w];
                }
            bv[blockIdx.x*5 + k] = sw_v[0];
            bi[blockIdx.x*5 + k] = sw_i[0];
            s_v[sw_p[0]] = -INFINITY;
        }
        __syncthreads();
    }
}

__global__ __launch_bounds__(256) void final_topk(
    const float* __restrict__ bv, const int* __restrict__ bi,
    float* __restrict__ out)
{
    __shared__ float s_v[NCAND];
    __shared__ int   s_i[NCAND];
    __shared__ float sw_v[4];
    __shared__ int   sw_i[4], sw_p[4];

    const int tid = threadIdx.x;
    for (int e = tid; e < NCAND; e += 256) { s_v[e] = bv[e]; s_i[e] = bi[e]; }
    __syncthreads();

    for (int k = 0; k < 5; k++) {
        float v = -INFINITY; int i = 0x7fffffff; int p = 0;
        for (int e = tid; e < NCAND; e += 256) {
            if (better(s_v[e], s_i[e], v, i)) { v = s_v[e]; i = s_i[e]; p = e; }
        }
        #pragma unroll
        for (int m = 32; m >= 1; m >>= 1) {
            float ov = __shfl_xor(v, m);
            int   oi = __shfl_xor(i, m);
            int   op = __shfl_xor(p, m);
            if (better(ov, oi, v, i)) { v = ov; i = oi; p = op; }
        }
        if ((tid & 63) == 0) { int w = tid >> 6; sw_v[w] = v; sw_i[w] = i; sw_p[w] = p; }
        __syncthreads();
        if (tid == 0) {
            for (int w = 1; w < 4; w++)
                if (better(sw_v[w], sw_i[w], sw_v[0], sw_i[0])) {
                    sw_v[0] = sw_v[w]; sw_i[0] = sw_i[w]; sw_p[0] = sw_p[w];
                }
            out[k]     = sw_v[0];
            out[5 + k] = (float)sw_i[0];
            s_v[sw_p[0]] = -INFINITY;
        }
        __syncthreads();
    }
}

extern "C" void kernel_launch(void* const* d_in, const int* in_sizes, int n_in,
                              void* d_out, int out_size, void* d_ws, size_t ws_size,
                              hipStream_t stream) {
    const float* W    = (const float*)d_in[0];
    const int*   qidx = (const int*)d_in[1];   // low word of int64 is correct (LE, V < 2^31)
    const int V = in_sizes[0] / 128;

    float* bv = (float*)d_ws;
    int*   bi = (int*)((char*)d_ws + (size_t)NB1 * 5 * sizeof(float));

    sim_block_topk<<<NB1, TPB, 0, stream>>>(W, qidx, V, bv, bi);
    final_topk<<<1, 256, 0, stream>>>(bv, bi, (float*)d_out);
}